// Round 1
// baseline (12.772 us; speedup 1.0000x reference)
//
#include <hip/hip_runtime.h>

#define FEAT 128
#define NP   256
#define NG   1024
#define PT   16
#define GT   16
#define LDP  132   // padded row stride (floats): breaks 512B bank alias, keeps 16B align
#define EPSB 1e-5f

__global__ __launch_bounds__(256) void CLASSIFIER_69956427317336_kernel(
    const float* __restrict__ px,   // [NP][FEAT]
    const float* __restrict__ gx,   // [NG][FEAT]
    const float* __restrict__ bw,   // [FEAT]
    const float* __restrict__ bb,   // [FEAT]
    const float* __restrict__ bm,   // [FEAT]
    const float* __restrict__ bv,   // [FEAT]
    const float* __restrict__ Wm,   // [2][FEAT]
    const float* __restrict__ bias, // [2]
    float* __restrict__ out)        // [NP][NG][2]
{
    __shared__ float xs[PT][LDP];
    __shared__ float ys[GT][LDP];
    __shared__ float V0[FEAT];
    __shared__ float V1[FEAT];
    __shared__ float kpart[4];
    __shared__ float Ksh[2];

    const int tid  = threadIdx.x;
    const int p0   = blockIdx.x * PT;
    const int g0   = blockIdx.y * GT;

    // ---- stage x-tile and y-tile (coalesced float4 global loads) ----
    {
        int t = tid;
        #pragma unroll
        for (int it = 0; it < 2; ++it, t += 256) {
            const int row = t >> 5;        // 0..15
            const int c4  = t & 31;        // float4 index within row
            float4 xv = *(const float4*)(px + (size_t)(p0 + row) * FEAT + c4 * 4);
            *(float4*)&xs[row][c4 * 4] = xv;
            float4 yv = *(const float4*)(gx + (size_t)(g0 + row) * FEAT + c4 * 4);
            *(float4*)&ys[row][c4 * 4] = yv;
        }
    }

    // ---- fold BN + linear: V[c][f] = bw*rsqrt(bv+eps)*W[c][f];
    //      K[c] = b[c] + sum_f (bb - bm*inv)*W[c][f]  (wave-reduced) ----
    {
        const int w    = tid >> 6;                 // wave 0..3
        const int lane = tid & 63;
        const int c    = w & 1;                    // waves 0,2 -> class0; 1,3 -> class1
        const int f    = lane + ((w >> 1) << 6);   // 0..63 or 64..127
        const float inv = bw[f] * rsqrtf(bv[f] + EPSB);
        const float wv  = Wm[c * FEAT + f];
        const float v   = inv * wv;
        if (c == 0) V0[f] = v; else V1[f] = v;
        float kcf = (bb[f] - bm[f] * inv) * wv;
        #pragma unroll
        for (int off = 32; off > 0; off >>= 1) kcf += __shfl_down(kcf, off);
        if (lane == 0) kpart[w] = kcf;
    }
    __syncthreads();
    if (tid < 2) Ksh[tid] = bias[tid] + kpart[tid] + kpart[tid + 2];
    __syncthreads();

    // ---- main: each thread computes one (p,g) pair, both classes ----
    const int gi = tid & (GT - 1);
    const int pi = tid >> 4;

    float acc0 = 0.f, acc1 = 0.f;
    #pragma unroll
    for (int f4 = 0; f4 < FEAT; f4 += 4) {
        const float4 xv = *(const float4*)&xs[pi][f4];
        const float4 yv = *(const float4*)&ys[gi][f4];
        const float4 v0 = *(const float4*)&V0[f4];
        const float4 v1 = *(const float4*)&V1[f4];
        float d, s;
        d = xv.x - yv.x; s = d * d;
        acc0 = fmaf(s, v0.x, acc0); acc1 = fmaf(s, v1.x, acc1);
        d = xv.y - yv.y; s = d * d;
        acc0 = fmaf(s, v0.y, acc0); acc1 = fmaf(s, v1.y, acc1);
        d = xv.z - yv.z; s = d * d;
        acc0 = fmaf(s, v0.z, acc0); acc1 = fmaf(s, v1.z, acc1);
        d = xv.w - yv.w; s = d * d;
        acc0 = fmaf(s, v0.w, acc0); acc1 = fmaf(s, v1.w, acc1);
    }

    const size_t o = ((size_t)(p0 + pi) * NG + (size_t)(g0 + gi)) * 2;
    *(float2*)(out + o) = make_float2(acc0 + Ksh[0], acc1 + Ksh[1]);
}

extern "C" void kernel_launch(void* const* d_in, const int* in_sizes, int n_in,
                              void* d_out, int out_size, void* d_ws, size_t ws_size,
                              hipStream_t stream) {
    const float* px = (const float*)d_in[0];
    const float* gx = (const float*)d_in[1];
    const float* bw = (const float*)d_in[2];
    const float* bb = (const float*)d_in[3];
    const float* bm = (const float*)d_in[4];
    const float* bv = (const float*)d_in[5];
    const float* Wm = (const float*)d_in[6];
    const float* bs = (const float*)d_in[7];
    float* out = (float*)d_out;

    dim3 grid(NP / PT, NG / GT);   // 16 x 64 = 1024 blocks
    dim3 block(256);
    CLASSIFIER_69956427317336_kernel<<<grid, block, 0, stream>>>(
        px, gx, bw, bb, bm, bv, Wm, bs, out);
}